// Round 10
// baseline (136.827 us; speedup 1.0000x reference)
//
#include <hip/hip_runtime.h>
#include <hip/hip_fp16.h>
#include <stdint.h>

typedef _Float16 f16;
typedef _Float16 f16x8 __attribute__((ext_vector_type(8)));
typedef _Float16 f16x4v __attribute__((ext_vector_type(4)));
typedef __fp16 h16x2 __attribute__((ext_vector_type(2)));   // cvt_pkrtz return type
typedef float f32x4 __attribute__((ext_vector_type(4)));
typedef float f32x16 __attribute__((ext_vector_type(16)));

#define MFMA32(a,b,c) __builtin_amdgcn_mfma_f32_32x32x16_f16(a,b,c,0,0,0)
#define CVTPK(a,b) __builtin_amdgcn_cvt_pkrtz(a,b)

#if __has_builtin(__builtin_amdgcn_exp2f)
#define EXP2(x) __builtin_amdgcn_exp2f(x)
#else
#define EXP2(x) exp2f(x)
#endif

static __device__ __forceinline__ float dot2acc(h16x2 a, float c) {
#if __has_builtin(__builtin_amdgcn_fdot2)
    const h16x2 one = { (__fp16)1.f, (__fp16)1.f };
    return __builtin_amdgcn_fdot2(a, one, c, false);
#else
    return c + (float)a[0] + (float)a[1];
#endif
}

typedef __attribute__((address_space(1))) void gvoid_t;
typedef __attribute__((address_space(3))) void svoid_t;
#define AS1(p) ((gvoid_t*)(uintptr_t)(p))
#define AS3(p) ((svoid_t*)(uint32_t)(uintptr_t)(p))

static constexpr int Bc = 2, Tc = 2048, Dc = 768, Hc = 12;
static constexpr int Mc = Bc * Tc;                      // 4096
static constexpr float SC2 = 0.18033688011112042f;      // (1/8) * log2(e), folded into Wq/bq

union PA { f16x8 v; h16x2 h[4]; };

// FRAG32: tiles [rows][8 chunks of 16B] (128B rows), storage chunk = logical ^ (row&7).
#define FRAG32(BASE, ROWOFF, CHUNK) \
    (*(const f16x8*)((const char*)(BASE) + \
        ((ROWOFF) + q32) * 128 + (((CHUNK) ^ g7) * 16)))

// FRAGP: row-pair layout for BK=32 tiles. Line L=row/2 (128B), chunk8 = (row&1)*4 + c16,
// stored at chunk8 ^ (L&7). ROWOFF must be a multiple of 32.
#define FRAGP(BASE, ROWOFF, C) \
    (*(const f16x8*)((const char*)(BASE) + \
        (((ROWOFF) / 2 + (q32 >> 1)) * 128) + \
        (((((q32 & 1) << 2) | (C)) ^ ((q32 >> 1) & 7)) * 16)))

// ------- 128x64 GEMM mainloop, BK=32, MFMA32, row-pair swizzled tiles, dbuf (24 KiB) -------
// A is f32 (reg-staged + cvt) when AF32, else f16 via global_load_lds. W is f32, reg-staged,
// scaled by wscl before cvt. As: 2 x 8 KiB. Bs: 2 x 4 KiB. acc[mi]: rows wr*64+mi*32.
template<bool AF32>
__device__ __forceinline__ void gemm_bk32_t(
    const void* Av, const float* __restrict__ W, float wscl,
    int brow, int bcol, char* As, char* Bs, f32x16 acc[2])
{
    const int tid = threadIdx.x;
    const int w = tid >> 6, lane = tid & 63;
    const int q32 = lane & 31, hi = lane >> 5;
    const int wr = w >> 1, wc = w & 1;
    const int wbase16 = (tid & ~63) * 16;

    int arow[2], akc[2];
#pragma unroll
    for (int j = 0; j < 2; ++j) {
        const int p = j * 256 + tid;
        const int L = p >> 3, c8 = (p & 7) ^ (L & 7);
        arow[j] = 2 * L + (c8 >> 2); akc[j] = (c8 & 3) * 8;
    }
    const int bL = tid >> 3, bc8 = (tid & 7) ^ (bL & 7);
    const int browW = 2 * bL + (bc8 >> 2), bkc = (bc8 & 3) * 8;

    float4 af[2][2], bw[2];

#define LOADW(KT_) do { \
    const float* wp_ = W + (size_t)(bcol + browW) * 768 + (KT_) * 32 + bkc; \
    bw[0] = *(const float4*)(wp_); bw[1] = *(const float4*)(wp_ + 4); } while (0)

#define LOADA(KT_) do { \
    _Pragma("unroll") \
    for (int j_ = 0; j_ < 2; ++j_) { \
        const float* ap_ = (const float*)Av + (size_t)(brow + arow[j_]) * 768 + (KT_) * 32 + akc[j_]; \
        af[j_][0] = *(const float4*)(ap_); af[j_][1] = *(const float4*)(ap_ + 4); } } while (0)

#define GLDSA(KT_, BUF_) do { \
    _Pragma("unroll") \
    for (int j_ = 0; j_ < 2; ++j_) \
        __builtin_amdgcn_global_load_lds( \
            AS1((const f16*)Av + (size_t)(brow + arow[j_]) * 768 + (KT_) * 32 + akc[j_]), \
            AS3(As + (BUF_) * 8192 + j_ * 4096 + wbase16), 16, 0, 0); } while (0)

#define WRITEW(BUF_) do { \
    f16x8 o_; \
    _Pragma("unroll") \
    for (int e_ = 0; e_ < 4; ++e_) o_[e_] = (f16)((&bw[0].x)[e_] * wscl); \
    _Pragma("unroll") \
    for (int e_ = 0; e_ < 4; ++e_) o_[4 + e_] = (f16)((&bw[1].x)[e_] * wscl); \
    *(f16x8*)(Bs + (BUF_) * 4096 + tid * 16) = o_; } while (0)

#define WRITEA(BUF_) do { \
    _Pragma("unroll") \
    for (int j_ = 0; j_ < 2; ++j_) { \
        f16x8 o_; \
        _Pragma("unroll") \
        for (int e_ = 0; e_ < 4; ++e_) o_[e_] = (f16)((&af[j_][0].x)[e_]); \
        _Pragma("unroll") \
        for (int e_ = 0; e_ < 4; ++e_) o_[4 + e_] = (f16)((&af[j_][1].x)[e_]); \
        *(f16x8*)(As + (BUF_) * 8192 + j_ * 4096 + tid * 16) = o_; } } while (0)

    LOADW(0);
    if constexpr (AF32) { LOADA(0); WRITEA(0); } else { GLDSA(0, 0); }
    WRITEW(0);
    __syncthreads();
    for (int kt = 0; kt < 24; ++kt) {
        const int cur = kt & 1;
        if (kt < 23) {
            LOADW(kt + 1);
            if constexpr (AF32) LOADA(kt + 1); else GLDSA(kt + 1, cur ^ 1);
        }
        const char* As_ = As + cur * 8192;
        const char* Bs_ = Bs + cur * 4096;
#pragma unroll
        for (int ks = 0; ks < 2; ++ks) {
            const f16x8 a0 = FRAGP(As_, wr * 64,      ks * 2 + hi);
            const f16x8 a1 = FRAGP(As_, wr * 64 + 32, ks * 2 + hi);
            const f16x8 bb = FRAGP(Bs_, wc * 32,      ks * 2 + hi);
            acc[0] = MFMA32(a0, bb, acc[0]);
            acc[1] = MFMA32(a1, bb, acc[1]);
        }
        if (kt < 23) {
            if constexpr (AF32) WRITEA(cur ^ 1);
            WRITEW(cur ^ 1);
        }
        __syncthreads();
    }
#undef LOADW
#undef LOADA
#undef GLDSA
#undef WRITEW
#undef WRITEA
}

// ---------------- QKV projections, f32 inputs (z: 0=Q-scaled, 1=K, 2=V via LDS transpose) ----------------
__global__ __launch_bounds__(256) void qkv_proj(
    const float* __restrict__ q, const float* __restrict__ k, const float* __restrict__ v,
    const float* __restrict__ Wq, const float* __restrict__ Wk, const float* __restrict__ Wv,
    const float* __restrict__ bq, const float* __restrict__ bk, const float* __restrict__ bv,
    f16* __restrict__ Qp, f16* __restrict__ Kp, f16* __restrict__ Vt)
{
    __shared__ char lds[24576];
    char* As = lds; char* Bs = lds + 16384;

    const int z = blockIdx.z;
    const float* A = (z == 0) ? q : (z == 1) ? k : v;
    const float* W = (z == 0) ? Wq : (z == 1) ? Wk : Wv;
    const float* bias = (z == 0) ? bq : (z == 1) ? bk : bv;
    const float wscl = (z == 0) ? SC2 : 1.f;
    const int brow = blockIdx.y * 128, bcol = blockIdx.x * 64;

    f32x16 acc[2];
#pragma unroll
    for (int mi = 0; mi < 2; ++mi)
#pragma unroll
        for (int r = 0; r < 16; ++r) acc[mi][r] = 0.f;

    gemm_bk32_t<true>(A, W, wscl, brow, bcol, As, Bs, acc);

    const int tid = threadIdx.x, w = tid >> 6, lane = tid & 63;
    const int q32 = lane & 31, hi = lane >> 5;
    const int wr = w >> 1, wc = w & 1;
    const int c = bcol + wc * 32 + q32;
    const float bval = (z == 0) ? bias[c] * SC2 : bias[c];

    if (z < 2) {
        f16* dst = (z == 0) ? Qp : Kp;
#pragma unroll
        for (int mi = 0; mi < 2; ++mi)
#pragma unroll
            for (int r = 0; r < 16; ++r) {
                const int row = brow + wr * 64 + mi * 32 + (r & 3) + 8 * (r >> 2) + 4 * hi;
                dst[(size_t)row * 768 + c] = (f16)(acc[mi][r] + bval);
            }
    } else {
        // V: transpose in LDS (reuse As region, 16 KiB), then coalesced stores.
        __syncthreads();
        const int dl = wc * 32 + q32;
#pragma unroll
        for (int mi = 0; mi < 2; ++mi)
#pragma unroll
            for (int j = 0; j < 8; ++j) {
                const int r0 = 2 * j;
                const int crow = (r0 & 3) + 8 * (r0 >> 2) + 4 * hi;     // even, < 32
                const int sw = ((crow >> 2) ^ (crow >> 3)) & 1;         // sigma involution
                const int tp = crow ^ (sw * 12);
                const int tloc = wr * 64 + mi * 32 + tp;
                const h16x2 pv = CVTPK(acc[mi][r0] + bval, acc[mi][r0 + 1] + bval);
                *(h16x2*)(As + dl * 256 + ((tloc * 2) ^ ((dl & 7) << 4))) = pv;
            }
        __syncthreads();
        const int bb = brow >> 11, t0 = brow & 2047, hh = bcol >> 6;
        f16* Vh = Vt + ((size_t)(bb * 12 + hh) * 64) * 2048;
#pragma unroll
        for (int j = 0; j < 4; ++j) {
            const int dr = j * 16 + (tid >> 4), off = tid & 15;
            const f16x8 vv = *(const f16x8*)(As + dr * 256 + ((off * 16) ^ ((dr & 7) << 4)));
            *(f16x8*)(Vh + (size_t)dr * 2048 + t0 + off * 8) = vv;
        }
    }
}

// ---------------- fused attention, 32x32x16 MFMA, 4 waves = (q-half, k-half) ----------------
__global__ __launch_bounds__(256, 3) void attn_out(
    const f16* __restrict__ Qp, const f16* __restrict__ Kp, const f16* __restrict__ Vt,
    float* __restrict__ l_inv, f16* __restrict__ ctx)
{
    __shared__ f16 Kbuf[2][4096];    // [64 k][8 chunks*8 f16], swizzled
    __shared__ f16 Vbuf[2][4096];    // [64 d][8 chunks*8 f16], swizzled (k sigma-permuted)
    __shared__ float Ored[2][32][64];  // [qh][q][d] partial O from kh=1 waves
    __shared__ float lred[2][2][32];   // [kh][qh][q]

    const int qt = blockIdx.x, h = blockIdx.y, b = blockIdx.z;
    const int tid = threadIdx.x, w = tid >> 6, lane = tid & 63;
    const int q32 = lane & 31, hi = lane >> 5, g7 = lane & 7;
    const int qh = w & 1, kh = w >> 1;
    const int wbase16 = (tid & ~63) * 16;

    const size_t qrow0 = (size_t)b * 2048 + qt * 64 + qh * 32;
    const int hcol = h * 64;

    const f16* qb = Qp + (qrow0 + q32) * 768 + hcol + hi * 8;
    f16x8 bqf[4];
#pragma unroll
    for (int d = 0; d < 4; ++d) bqf[d] = *(const f16x8*)(qb + d * 16);

    const size_t kbase = (size_t)b * 2048;
    const f16* Vg = Vt + ((size_t)(b * 12 + h)) * 64 * 2048;

    f32x16 oacc[2];
#pragma unroll
    for (int dt = 0; dt < 2; ++dt)
#pragma unroll
        for (int r = 0; r < 16; ++r) oacc[dt][r] = 0.f;
    float lsum = 0.f;

#define STAGE_KV(KT_, BUF) do { \
    _Pragma("unroll") \
    for (int j_ = 0; j_ < 2; ++j_) { \
        const int p_ = j_ * 256 + tid; \
        const int row_ = p_ >> 3, c_ = (p_ & 7) ^ (row_ & 7); \
        __builtin_amdgcn_global_load_lds( \
            AS1(Kp + (kbase + (size_t)(KT_) * 64 + row_) * 768 + hcol + c_ * 8), \
            AS3((char*)&Kbuf[BUF][0] + j_ * 4096 + wbase16), 16, 0, 0); \
        __builtin_amdgcn_global_load_lds( \
            AS1(Vg + (size_t)row_ * 2048 + (KT_) * 64 + c_ * 8), \
            AS3((char*)&Vbuf[BUF][0] + j_ * 4096 + wbase16), 16, 0, 0); \
    } } while (0)

#define AOBODY(CUR) do { \
    const f16* Kb_ = &Kbuf[CUR][0]; const f16* Vb_ = &Vbuf[CUR][0]; \
    f32x16 sa; \
    _Pragma("unroll") \
    for (int r_ = 0; r_ < 16; ++r_) sa[r_] = 0.f; \
    sa = MFMA32(FRAG32(Kb_, kh * 32, 0 + hi), bqf[0], sa); \
    sa = MFMA32(FRAG32(Kb_, kh * 32, 2 + hi), bqf[1], sa); \
    sa = MFMA32(FRAG32(Kb_, kh * 32, 4 + hi), bqf[2], sa); \
    sa = MFMA32(FRAG32(Kb_, kh * 32, 6 + hi), bqf[3], sa); \
    float p[16]; \
    _Pragma("unroll") \
    for (int r_ = 0; r_ < 16; ++r_) p[r_] = EXP2(sa[r_]); \
    PA pa0, pa1; \
    pa0.h[0] = CVTPK(p[0], p[1]);   pa0.h[1] = CVTPK(p[2], p[3]); \
    pa0.h[2] = CVTPK(p[4], p[5]);   pa0.h[3] = CVTPK(p[6], p[7]); \
    pa1.h[0] = CVTPK(p[8], p[9]);   pa1.h[1] = CVTPK(p[10], p[11]); \
    pa1.h[2] = CVTPK(p[12], p[13]); pa1.h[3] = CVTPK(p[14], p[15]); \
    float t0_ = 0.f, t1_ = 0.f; \
    t0_ = dot2acc(pa0.h[0], t0_); t0_ = dot2acc(pa0.h[1], t0_); \
    t0_ = dot2acc(pa0.h[2], t0_); t0_ = dot2acc(pa0.h[3], t0_); \
    t1_ = dot2acc(pa1.h[0], t1_); t1_ = dot2acc(pa1.h[1], t1_); \
    t1_ = dot2acc(pa1.h[2], t1_); t1_ = dot2acc(pa1.h[3], t1_); \
    lsum += t0_ + t1_; \
    oacc[0] = MFMA32(FRAG32(Vb_, 0,  kh * 4 + 0 + hi), pa0.v, oacc[0]); \
    oacc[0] = MFMA32(FRAG32(Vb_, 0,  kh * 4 + 2 + hi), pa1.v, oacc[0]); \
    oacc[1] = MFMA32(FRAG32(Vb_, 32, kh * 4 + 0 + hi), pa0.v, oacc[1]); \
    oacc[1] = MFMA32(FRAG32(Vb_, 32, kh * 4 + 2 + hi), pa1.v, oacc[1]); \
} while (0)

    STAGE_KV(0, 0);
    __syncthreads();
    for (int kt = 0; kt < 32; ++kt) {
        const int cur = kt & 1;
        if (kt < 31) STAGE_KV(kt + 1, cur ^ 1);
        AOBODY(cur);
        __syncthreads();
    }
#undef STAGE_KV
#undef AOBODY

    // ---- cross-wave reduction: combine k-halves ----
    lsum += __shfl_xor(lsum, 32);
    if (hi == 0) lred[kh][qh][q32] = lsum;
    if (kh == 1) {
#pragma unroll
        for (int dt = 0; dt < 2; ++dt)
#pragma unroll
            for (int g = 0; g < 4; ++g) {
                float4 v4 = { oacc[dt][g * 4 + 0], oacc[dt][g * 4 + 1],
                              oacc[dt][g * 4 + 2], oacc[dt][g * 4 + 3] };
                *(float4*)&Ored[qh][q32][dt * 32 + g * 8 + hi * 4] = v4;
            }
    }
    __syncthreads();
    if (kh == 0) {
        const float iv = 1.f / (lred[0][qh][q32] + lred[1][qh][q32]);
        if (hi == 0)
            l_inv[((size_t)(b * 12 + h)) * 2048 + qt * 64 + qh * 32 + q32] = iv;
        f16* cb = ctx + (qrow0 + q32) * 768 + hcol;
#pragma unroll
        for (int dt = 0; dt < 2; ++dt)
#pragma unroll
            for (int g = 0; g < 4; ++g) {
                const int d0 = dt * 32 + g * 8 + hi * 4;
                const float4 o4 = *(const float4*)&Ored[qh][q32][d0];
                f16x4v s;
#pragma unroll
                for (int e = 0; e < 4; ++e)
                    s[e] = (f16)((oacc[dt][g * 4 + e] + (&o4.x)[e]) * iv);
                *(f16x4v*)(cb + d0) = s;
            }
    }
}

// ------- fused tail: blocks [0,384) = out_proj (BK32 gemm, f32 Wo), [384,2432) = attn_mean 64x64 -------
__global__ __launch_bounds__(256) void tail_fused(
    const f16* __restrict__ ctx, const float* __restrict__ Wo,
    const float* __restrict__ bo, float* __restrict__ out,
    const f16* __restrict__ Qp, const f16* __restrict__ Kp,
    const float* __restrict__ l_inv, float* __restrict__ om)
{
    __shared__ char sh[32768];   // 32 KiB

    const int tid = threadIdx.x, w = tid >> 6, lane = tid & 63;
    const int q32 = lane & 31, hi = lane >> 5, g7 = lane & 7;
    const int wbase16 = (tid & ~63) * 16;

    if (blockIdx.x < 384) {
        // ================= out_proj =================
        const int brow = (blockIdx.x / 12) * 128, bcol = (blockIdx.x % 12) * 64;
        f32x16 acc[2];
#pragma unroll
        for (int mi = 0; mi < 2; ++mi)
#pragma unroll
            for (int r = 0; r < 16; ++r) acc[mi][r] = 0.f;

        gemm_bk32_t<false>(ctx, Wo, 1.f, brow, bcol, sh, sh + 16384, acc);

        const int wr = w >> 1, wc = w & 1;
        const int c = bcol + wc * 32 + q32;
        const float bval = bo[c];
#pragma unroll
        for (int mi = 0; mi < 2; ++mi)
#pragma unroll
            for (int r = 0; r < 16; ++r) {
                const int row = brow + wr * 64 + mi * 32 + (r & 3) + 8 * (r >> 2) + 4 * hi;
                out[(size_t)row * 768 + c] = acc[mi][r] + bval;
            }
    } else {
        // ================= attn_mean: 64 q x 64 k per block, 4 waves = (qh, kh) =================
        const int mb = blockIdx.x - 384;              // [0, 2048)
        const int kt = mb & 31, r2 = mb >> 5;
        const int qt = r2 & 31, b = r2 >> 5;
        const int qh = w & 1, kh = w >> 1;

        char* Qb = sh;            // 2 x 8 KiB
        char* Kb = sh + 16384;    // 2 x 8 KiB

        const size_t qtrow = (size_t)b * 2048 + qt * 64;
        const size_t ktrow = (size_t)b * 2048 + kt * 64;

        f32x16 macc;
#pragma unroll
        for (int r = 0; r < 16; ++r) macc[r] = 0.f;

#define MSTAGE(H_, BUF) do { \
    _Pragma("unroll") \
    for (int j_ = 0; j_ < 2; ++j_) { \
        const int p_ = j_ * 256 + tid; \
        const int row_ = p_ >> 3, c_ = (p_ & 7) ^ (row_ & 7); \
        __builtin_amdgcn_global_load_lds( \
            AS1(Qp + (qtrow + row_) * 768 + (H_) * 64 + c_ * 8), \
            AS3(Qb + (BUF) * 8192 + j_ * 4096 + wbase16), 16, 0, 0); \
        __builtin_amdgcn_global_load_lds( \
            AS1(Kp + (ktrow + row_) * 768 + (H_) * 64 + c_ * 8), \
            AS3(Kb + (BUF) * 8192 + j_ * 4096 + wbase16), 16, 0, 0); \
    } } while (0)

#define MBODY(H_, CUR) do { \
    const f16* Qb_ = (const f16*)(Qb + (CUR) * 8192); \
    const f16* Kb_ = (const f16*)(Kb + (CUR) * 8192); \
    f16x8 qf[4]; \
    _Pragma("unroll") \
    for (int d_ = 0; d_ < 4; ++d_) qf[d_] = FRAG32(Qb_, qh * 32, d_ * 2 + hi); \
    f32x16 sa; \
    _Pragma("unroll") \
    for (int r_ = 0; r_ < 16; ++r_) sa[r_] = 0.f; \
    sa = MFMA32(FRAG32(Kb_, kh * 32, 0 + hi), qf[0], sa); \
    sa = MFMA32(FRAG32(Kb_, kh * 32, 2 + hi), qf[1], sa); \
    sa = MFMA32(FRAG32(Kb_, kh * 32, 4 + hi), qf[2], sa); \
    sa = MFMA32(FRAG32(Kb_, kh * 32, 6 + hi), qf[3], sa); \
    const float ivv = l_inv[((size_t)(b * 12 + (H_))) * 2048 + qt * 64 + qh * 32 + q32]; \
    _Pragma("unroll") \
    for (int r_ = 0; r_ < 16; ++r_) macc[r_] += EXP2(sa[r_]) * ivv; \
} while (0)

        MSTAGE(0, 0);
        __syncthreads();
        for (int h = 0; h < 12; ++h) {
            const int cur = h & 1;
            if (h < 11) MSTAGE(h + 1, cur ^ 1);
            MBODY(h, cur);
            __syncthreads();
        }
#undef MSTAGE
#undef MBODY

        float* ob = om + ((size_t)(b * 2048 + qt * 64 + qh * 32 + q32)) * 2048
                  + kt * 64 + kh * 32;
#pragma unroll
        for (int g = 0; g < 4; ++g) {
            float4 v4 = { macc[g * 4 + 0] * (1.0f / 12.0f),
                          macc[g * 4 + 1] * (1.0f / 12.0f),
                          macc[g * 4 + 2] * (1.0f / 12.0f),
                          macc[g * 4 + 3] * (1.0f / 12.0f) };
            *(float4*)(ob + g * 8 + hi * 4) = v4;
        }
    }
}

// ---------------- launch ----------------
extern "C" void kernel_launch(void* const* d_in, const int* in_sizes, int n_in,
                              void* d_out, int out_size, void* d_ws, size_t ws_size,
                              hipStream_t stream) {
    const float* q  = (const float*)d_in[0];
    const float* k  = (const float*)d_in[1];
    const float* v  = (const float*)d_in[2];
    const float* Wq = (const float*)d_in[3];
    const float* bq = (const float*)d_in[4];
    const float* Wk = (const float*)d_in[5];
    const float* bk = (const float*)d_in[6];
    const float* Wv = (const float*)d_in[7];
    const float* bv = (const float*)d_in[8];
    const float* Wo = (const float*)d_in[9];
    const float* bo = (const float*)d_in[10];
    float* out = (float*)d_out;

    char* ws = (char*)d_ws;
    const size_t SZ_IN = (size_t)Mc * Dc * 2;   // 6291456 bytes
    f16* ctx   = (f16*)(ws);
    float* l_inv = (float*)(ws + SZ_IN);
    f16* Qp    = (f16*)(ws + 2 * SZ_IN);
    f16* Kp    = (f16*)(ws + 3 * SZ_IN);
    f16* Vt    = (f16*)(ws + 4 * SZ_IN);

    qkv_proj<<<dim3(12, 32, 3), dim3(256), 0, stream>>>(q, k, v, Wq, Wk, Wv,
                                                        bq, bk, bv, Qp, Kp, Vt);
    attn_out<<<dim3(32, 12, 2), dim3(256), 0, stream>>>(Qp, Kp, Vt, l_inv, ctx);
    tail_fused<<<dim3(2432), dim3(256), 0, stream>>>(ctx, Wo, bo, out,
                                                     Qp, Kp, l_inv,
                                                     out + (size_t)Mc * Dc);
}

// Round 11
// 130.655 us; speedup vs baseline: 1.0472x; 1.0472x over previous
//
#include <hip/hip_runtime.h>
#include <hip/hip_fp16.h>
#include <stdint.h>

typedef _Float16 f16;
typedef _Float16 f16x8 __attribute__((ext_vector_type(8)));
typedef _Float16 f16x4v __attribute__((ext_vector_type(4)));
typedef __fp16 h16x2 __attribute__((ext_vector_type(2)));   // cvt_pkrtz return type
typedef float f32x4 __attribute__((ext_vector_type(4)));
typedef float f32x16 __attribute__((ext_vector_type(16)));

#define MFMA32(a,b,c) __builtin_amdgcn_mfma_f32_32x32x16_f16(a,b,c,0,0,0)
#define CVTPK(a,b) __builtin_amdgcn_cvt_pkrtz(a,b)

#if __has_builtin(__builtin_amdgcn_exp2f)
#define EXP2(x) __builtin_amdgcn_exp2f(x)
#else
#define EXP2(x) exp2f(x)
#endif

static __device__ __forceinline__ float dot2acc(h16x2 a, float c) {
#if __has_builtin(__builtin_amdgcn_fdot2)
    const h16x2 one = { (__fp16)1.f, (__fp16)1.f };
    return __builtin_amdgcn_fdot2(a, one, c, false);
#else
    return c + (float)a[0] + (float)a[1];
#endif
}

typedef __attribute__((address_space(1))) void gvoid_t;
typedef __attribute__((address_space(3))) void svoid_t;
#define AS1(p) ((gvoid_t*)(uintptr_t)(p))
#define AS3(p) ((svoid_t*)(uint32_t)(uintptr_t)(p))

static constexpr int Bc = 2, Tc = 2048, Dc = 768, Hc = 12;
static constexpr int Mc = Bc * Tc;                      // 4096
static constexpr float SC2 = 0.18033688011112042f;      // (1/8) * log2(e), folded into Wq/bq

union PA { f16x8 v; h16x2 h[4]; };

// FRAG32: tiles [rows][8 chunks of 16B] (128B rows), storage chunk = logical ^ (row&7).
#define FRAG32(BASE, ROWOFF, CHUNK) \
    (*(const f16x8*)((const char*)(BASE) + \
        ((ROWOFF) + q32) * 128 + (((CHUNK) ^ g7) * 16)))

// FRAGP: row-pair layout for BK=32 tiles. Line L=row/2 (128B), chunk8 = (row&1)*4 + c16,
// stored at chunk8 ^ (L&7). ROWOFF must be a multiple of 32.
#define FRAGP(BASE, ROWOFF, C) \
    (*(const f16x8*)((const char*)(BASE) + \
        (((ROWOFF) / 2 + (q32 >> 1)) * 128) + \
        (((((q32 & 1) << 2) | (C)) ^ ((q32 >> 1) & 7)) * 16)))

// ---------------- f32 -> f16 conversion (all inputs + weights; Wq pre-scaled) ----------------
__global__ __launch_bounds__(256) void conv_all(
    const float* __restrict__ q, const float* __restrict__ k, const float* __restrict__ v,
    const float* __restrict__ wq, const float* __restrict__ wk, const float* __restrict__ wv,
    const float* __restrict__ wo,
    f16* __restrict__ qh, f16* __restrict__ kh, f16* __restrict__ vh,
    f16* __restrict__ wqh, f16* __restrict__ wkh, f16* __restrict__ wvh, f16* __restrict__ woh)
{
    const int NI = (Mc * Dc) / 4;
    const int NW = (Dc * Dc) / 4;
    int i = blockIdx.x * 256 + threadIdx.x;
    if (i >= 3 * NI + 4 * NW) return;
    const float4* src; f16* dst; int j; float scl = 1.f;
    if (i < 3 * NI) {
        int a = i / NI; j = i - a * NI;
        src = (const float4*)(a == 0 ? q : (a == 1 ? k : v));
        dst = (a == 0 ? qh : (a == 1 ? kh : vh));
    } else {
        int t = i - 3 * NI;
        int a = t / NW; j = t - a * NW;
        src = (const float4*)(a == 0 ? wq : (a == 1 ? wk : (a == 2 ? wv : wo)));
        dst = (a == 0 ? wqh : (a == 1 ? wkh : (a == 2 ? wvh : woh)));
        if (a == 0) scl = SC2;
    }
    float4 f = src[j];
    f16x4v o = { (f16)(f.x * scl), (f16)(f.y * scl), (f16)(f.z * scl), (f16)(f.w * scl) };
    *(f16x4v*)(dst + 4 * j) = o;
}

// ------- 128x64 GEMM mainloop, BK=32, MFMA32, row-pair swizzled tiles, dbuf (24 KiB) -------
// As: 2 x 8 KiB (A tile 128x32). Bs: 2 x 4 KiB (W tile 64x32). acc[mi]: rows wr*64+mi*32.
__device__ __forceinline__ void gemm_bk32(
    const f16* __restrict__ A, const f16* __restrict__ W,
    int brow, int bcol, char* As, char* Bs, f32x16 acc[2])
{
    const int tid = threadIdx.x;
    const int w = tid >> 6, lane = tid & 63;
    const int q32 = lane & 31, hi = lane >> 5;
    const int wr = w >> 1, wc = w & 1;
    const int wbase16 = (tid & ~63) * 16;

#define GSA(KT_, BUF_) do { \
    const int k0_ = (KT_) * 32; \
    _Pragma("unroll") \
    for (int j_ = 0; j_ < 2; ++j_) { \
        const int p_ = j_ * 256 + tid; \
        const int L_ = p_ >> 3, c8_ = (p_ & 7) ^ (L_ & 7); \
        const int row_ = 2 * L_ + (c8_ >> 2), kc_ = (c8_ & 3) * 8; \
        __builtin_amdgcn_global_load_lds(AS1(A + (size_t)(brow + row_) * 768 + k0_ + kc_), \
            AS3(As + (BUF_) * 8192 + j_ * 4096 + wbase16), 16, 0, 0); \
    } } while (0)
#define GSB(KT_, BUF_) do { \
    const int k0_ = (KT_) * 32; \
    const int L_ = tid >> 3, c8_ = (tid & 7) ^ (L_ & 7); \
    const int row_ = 2 * L_ + (c8_ >> 2), kc_ = (c8_ & 3) * 8; \
    __builtin_amdgcn_global_load_lds(AS1(W + (size_t)(bcol + row_) * 768 + k0_ + kc_), \
        AS3(Bs + (BUF_) * 4096 + wbase16), 16, 0, 0); \
    } while (0)

    GSA(0, 0); GSB(0, 0);
    __syncthreads();
    for (int kt = 0; kt < 24; ++kt) {
        const int cur = kt & 1;
        if (kt < 23) { GSA(kt + 1, cur ^ 1); GSB(kt + 1, cur ^ 1); }
        const char* As_ = As + cur * 8192;
        const char* Bs_ = Bs + cur * 4096;
#pragma unroll
        for (int ks = 0; ks < 2; ++ks) {
            const f16x8 af0 = FRAGP(As_, wr * 64,      ks * 2 + hi);
            const f16x8 af1 = FRAGP(As_, wr * 64 + 32, ks * 2 + hi);
            const f16x8 bf  = FRAGP(Bs_, wc * 32,      ks * 2 + hi);
            acc[0] = MFMA32(af0, bf, acc[0]);
            acc[1] = MFMA32(af1, bf, acc[1]);
        }
        __syncthreads();
    }
#undef GSA
#undef GSB
}

// ---------------- QKV projections (z: 0=Q-scaled, 1=K, 2=V via LDS transpose) ----------------
__global__ __launch_bounds__(256) void qkv_proj(
    const f16* __restrict__ qh, const f16* __restrict__ kh, const f16* __restrict__ vh,
    const f16* __restrict__ wqh, const f16* __restrict__ wkh, const f16* __restrict__ wvh,
    const float* __restrict__ bq, const float* __restrict__ bk, const float* __restrict__ bv,
    f16* __restrict__ Qp, f16* __restrict__ Kp, f16* __restrict__ Vt)
{
    __shared__ char lds[24576];
    char* As = lds; char* Bs = lds + 16384;

    const int z = blockIdx.z;
    const f16* A = (z == 0) ? qh : (z == 1) ? kh : vh;
    const f16* W = (z == 0) ? wqh : (z == 1) ? wkh : wvh;
    const float* bias = (z == 0) ? bq : (z == 1) ? bk : bv;
    const int brow = blockIdx.y * 128, bcol = blockIdx.x * 64;

    f32x16 acc[2];
#pragma unroll
    for (int mi = 0; mi < 2; ++mi)
#pragma unroll
        for (int r = 0; r < 16; ++r) acc[mi][r] = 0.f;

    gemm_bk32(A, W, brow, bcol, As, Bs, acc);

    const int tid = threadIdx.x, w = tid >> 6, lane = tid & 63;
    const int q32 = lane & 31, hi = lane >> 5;
    const int wr = w >> 1, wc = w & 1;
    const int c = bcol + wc * 32 + q32;
    const float bval = (z == 0) ? bias[c] * SC2 : bias[c];

    if (z < 2) {
        f16* dst = (z == 0) ? Qp : Kp;
#pragma unroll
        for (int mi = 0; mi < 2; ++mi)
#pragma unroll
            for (int r = 0; r < 16; ++r) {
                const int row = brow + wr * 64 + mi * 32 + (r & 3) + 8 * (r >> 2) + 4 * hi;
                dst[(size_t)row * 768 + c] = (f16)(acc[mi][r] + bval);
            }
    } else {
        // V: transpose in LDS (reuse As region, 16 KiB), then coalesced stores.
        __syncthreads();
        const int dl = wc * 32 + q32;
#pragma unroll
        for (int mi = 0; mi < 2; ++mi)
#pragma unroll
            for (int j = 0; j < 8; ++j) {
                const int r0 = 2 * j;
                const int crow = (r0 & 3) + 8 * (r0 >> 2) + 4 * hi;     // even, < 32
                const int sw = ((crow >> 2) ^ (crow >> 3)) & 1;         // sigma involution
                const int tp = crow ^ (sw * 12);
                const int tloc = wr * 64 + mi * 32 + tp;
                const h16x2 pv = CVTPK(acc[mi][r0] + bval, acc[mi][r0 + 1] + bval);
                *(h16x2*)(As + dl * 256 + ((tloc * 2) ^ ((dl & 7) << 4))) = pv;
            }
        __syncthreads();
        const int bb = brow >> 11, t0 = brow & 2047, hh = bcol >> 6;
        f16* Vh = Vt + ((size_t)(bb * 12 + hh) * 64) * 2048;
#pragma unroll
        for (int j = 0; j < 4; ++j) {
            const int dr = j * 16 + (tid >> 4), off = tid & 15;
            const f16x8 vv = *(const f16x8*)(As + dr * 256 + ((off * 16) ^ ((dr & 7) << 4)));
            *(f16x8*)(Vh + (size_t)dr * 2048 + t0 + off * 8) = vv;
        }
    }
}

// ---------------- fused attention, 32x32x16 MFMA, 4 waves = (q-half, k-half) ----------------
// LDS: single 33 KiB arena. Main loop uses Kbuf/Vbuf (32 KiB); epilogue reuses the same
// bytes as Ored (16 KiB) + lred (after last main-loop barrier both phases are disjoint).
__global__ __launch_bounds__(256, 4) void attn_out(
    const f16* __restrict__ Qp, const f16* __restrict__ Kp, const f16* __restrict__ Vt,
    float* __restrict__ l_inv, f16* __restrict__ ctx)
{
    __shared__ char arena[33280];   // 32 KiB Kbuf/Vbuf  |  epilogue: Ored 16 KiB + lred 512 B

    f16* Kbuf0 = (f16*)(arena);            // [4096]
    f16* Kbuf1 = (f16*)(arena + 8192);
    f16* Vbuf0 = (f16*)(arena + 16384);
    f16* Vbuf1 = (f16*)(arena + 24576);
    float (*Ored)[32][64] = (float (*)[32][64])(arena);          // [2][32][64]
    float (*lred)[2][32]  = (float (*)[2][32])(arena + 16384);   // [2][2][32]

    const int qt = blockIdx.x, h = blockIdx.y, b = blockIdx.z;
    const int tid = threadIdx.x, w = tid >> 6, lane = tid & 63;
    const int q32 = lane & 31, hi = lane >> 5, g7 = lane & 7;
    const int qh = w & 1, kh = w >> 1;
    const int wbase16 = (tid & ~63) * 16;

    const size_t qrow0 = (size_t)b * 2048 + qt * 64 + qh * 32;
    const int hcol = h * 64;

    const f16* qb = Qp + (qrow0 + q32) * 768 + hcol + hi * 8;
    f16x8 bqf[4];
#pragma unroll
    for (int d = 0; d < 4; ++d) bqf[d] = *(const f16x8*)(qb + d * 16);

    const size_t kbase = (size_t)b * 2048;
    const f16* Vg = Vt + ((size_t)(b * 12 + h)) * 64 * 2048;

    f32x16 oacc[2];
#pragma unroll
    for (int dt = 0; dt < 2; ++dt)
#pragma unroll
        for (int r = 0; r < 16; ++r) oacc[dt][r] = 0.f;
    float lsum = 0.f;

#define STAGE_KV(KT_, KB_, VB_) do { \
    _Pragma("unroll") \
    for (int j_ = 0; j_ < 2; ++j_) { \
        const int p_ = j_ * 256 + tid; \
        const int row_ = p_ >> 3, c_ = (p_ & 7) ^ (row_ & 7); \
        __builtin_amdgcn_global_load_lds( \
            AS1(Kp + (kbase + (size_t)(KT_) * 64 + row_) * 768 + hcol + c_ * 8), \
            AS3((char*)(KB_) + j_ * 4096 + wbase16), 16, 0, 0); \
        __builtin_amdgcn_global_load_lds( \
            AS1(Vg + (size_t)row_ * 2048 + (KT_) * 64 + c_ * 8), \
            AS3((char*)(VB_) + j_ * 4096 + wbase16), 16, 0, 0); \
    } } while (0)

#define AOBODY(KB_, VB_) do { \
    const f16* Kb_ = (KB_); const f16* Vb_ = (VB_); \
    f32x16 sa; \
    _Pragma("unroll") \
    for (int r_ = 0; r_ < 16; ++r_) sa[r_] = 0.f; \
    sa = MFMA32(FRAG32(Kb_, kh * 32, 0 + hi), bqf[0], sa); \
    sa = MFMA32(FRAG32(Kb_, kh * 32, 2 + hi), bqf[1], sa); \
    sa = MFMA32(FRAG32(Kb_, kh * 32, 4 + hi), bqf[2], sa); \
    sa = MFMA32(FRAG32(Kb_, kh * 32, 6 + hi), bqf[3], sa); \
    float p[16]; \
    _Pragma("unroll") \
    for (int r_ = 0; r_ < 16; ++r_) p[r_] = EXP2(sa[r_]); \
    PA pa0, pa1; \
    pa0.h[0] = CVTPK(p[0], p[1]);   pa0.h[1] = CVTPK(p[2], p[3]); \
    pa0.h[2] = CVTPK(p[4], p[5]);   pa0.h[3] = CVTPK(p[6], p[7]); \
    pa1.h[0] = CVTPK(p[8], p[9]);   pa1.h[1] = CVTPK(p[10], p[11]); \
    pa1.h[2] = CVTPK(p[12], p[13]); pa1.h[3] = CVTPK(p[14], p[15]); \
    float t0_ = 0.f, t1_ = 0.f; \
    t0_ = dot2acc(pa0.h[0], t0_); t0_ = dot2acc(pa0.h[1], t0_); \
    t0_ = dot2acc(pa0.h[2], t0_); t0_ = dot2acc(pa0.h[3], t0_); \
    t1_ = dot2acc(pa1.h[0], t1_); t1_ = dot2acc(pa1.h[1], t1_); \
    t1_ = dot2acc(pa1.h[2], t1_); t1_ = dot2acc(pa1.h[3], t1_); \
    lsum += t0_ + t1_; \
    oacc[0] = MFMA32(FRAG32(Vb_, 0,  kh * 4 + 0 + hi), pa0.v, oacc[0]); \
    oacc[0] = MFMA32(FRAG32(Vb_, 0,  kh * 4 + 2 + hi), pa1.v, oacc[0]); \
    oacc[1] = MFMA32(FRAG32(Vb_, 32, kh * 4 + 0 + hi), pa0.v, oacc[1]); \
    oacc[1] = MFMA32(FRAG32(Vb_, 32, kh * 4 + 2 + hi), pa1.v, oacc[1]); \
} while (0)

    STAGE_KV(0, Kbuf0, Vbuf0);
    __syncthreads();
    for (int kt = 0; kt < 32; kt += 2) {
        STAGE_KV(kt + 1, Kbuf1, Vbuf1);
        AOBODY(Kbuf0, Vbuf0);
        __syncthreads();
        if (kt < 30) STAGE_KV(kt + 2, Kbuf0, Vbuf0);
        AOBODY(Kbuf1, Vbuf1);
        __syncthreads();
    }
#undef STAGE_KV
#undef AOBODY

    // ---- epilogue: arena reused as Ored/lred (all Kbuf/Vbuf reads completed) ----
    lsum += __shfl_xor(lsum, 32);
    if (hi == 0) lred[kh][qh][q32] = lsum;
    if (kh == 1) {
#pragma unroll
        for (int dt = 0; dt < 2; ++dt)
#pragma unroll
            for (int g = 0; g < 4; ++g) {
                float4 v4 = { oacc[dt][g * 4 + 0], oacc[dt][g * 4 + 1],
                              oacc[dt][g * 4 + 2], oacc[dt][g * 4 + 3] };
                *(float4*)&Ored[qh][q32][dt * 32 + g * 8 + hi * 4] = v4;
            }
    }
    __syncthreads();
    if (kh == 0) {
        const float iv = 1.f / (lred[0][qh][q32] + lred[1][qh][q32]);
        if (hi == 0)
            l_inv[((size_t)(b * 12 + h)) * 2048 + qt * 64 + qh * 32 + q32] = iv;
        f16* cb = ctx + (qrow0 + q32) * 768 + hcol;
#pragma unroll
        for (int dt = 0; dt < 2; ++dt)
#pragma unroll
            for (int g = 0; g < 4; ++g) {
                const int d0 = dt * 32 + g * 8 + hi * 4;
                const float4 o4 = *(const float4*)&Ored[qh][q32][d0];
                f16x4v s;
#pragma unroll
                for (int e = 0; e < 4; ++e)
                    s[e] = (f16)((oacc[dt][g * 4 + e] + (&o4.x)[e]) * iv);
                *(f16x4v*)(cb + d0) = s;
            }
    }
}

// ------- fused tail: blocks [0,384) = out_proj (BK32 gemm), [384,2432) = attn_mean 64x64 -------
__global__ __launch_bounds__(256) void tail_fused(
    const f16* __restrict__ ctx, const f16* __restrict__ woh,
    const float* __restrict__ bo, float* __restrict__ out,
    const f16* __restrict__ Qp, const f16* __restrict__ Kp,
    const float* __restrict__ l_inv, float* __restrict__ om)
{
    __shared__ char sh[32768];   // 32 KiB

    const int tid = threadIdx.x, w = tid >> 6, lane = tid & 63;
    const int q32 = lane & 31, hi = lane >> 5, g7 = lane & 7;
    const int wbase16 = (tid & ~63) * 16;

    if (blockIdx.x < 384) {
        // ================= out_proj =================
        const int brow = (blockIdx.x / 12) * 128, bcol = (blockIdx.x % 12) * 64;
        f32x16 acc[2];
#pragma unroll
        for (int mi = 0; mi < 2; ++mi)
#pragma unroll
            for (int r = 0; r < 16; ++r) acc[mi][r] = 0.f;

        gemm_bk32(ctx, woh, brow, bcol, sh, sh + 16384, acc);

        const int wr = w >> 1, wc = w & 1;
        const int c = bcol + wc * 32 + q32;
        const float bval = bo[c];
#pragma unroll
        for (int mi = 0; mi < 2; ++mi)
#pragma unroll
            for (int r = 0; r < 16; ++r) {
                const int row = brow + wr * 64 + mi * 32 + (r & 3) + 8 * (r >> 2) + 4 * hi;
                out[(size_t)row * 768 + c] = acc[mi][r] + bval;
            }
    } else {
        // ================= attn_mean: 64 q x 64 k per block, 4 waves = (qh, kh) =================
        const int mb = blockIdx.x - 384;              // [0, 2048)
        const int kt = mb & 31, r2 = mb >> 5;
        const int qt = r2 & 31, b = r2 >> 5;
        const int qh = w & 1, kh = w >> 1;

        char* Qb = sh;            // 2 x 8 KiB
        char* Kb = sh + 16384;    // 2 x 8 KiB

        const size_t qtrow = (size_t)b * 2048 + qt * 64;
        const size_t ktrow = (size_t)b * 2048 + kt * 64;

        f32x16 macc;
#pragma unroll
        for (int r = 0; r < 16; ++r) macc[r] = 0.f;

#define MSTAGE(H_, BUF) do { \
    _Pragma("unroll") \
    for (int j_ = 0; j_ < 2; ++j_) { \
        const int p_ = j_ * 256 + tid; \
        const int row_ = p_ >> 3, c_ = (p_ & 7) ^ (row_ & 7); \
        __builtin_amdgcn_global_load_lds( \
            AS1(Qp + (qtrow + row_) * 768 + (H_) * 64 + c_ * 8), \
            AS3(Qb + (BUF) * 8192 + j_ * 4096 + wbase16), 16, 0, 0); \
        __builtin_amdgcn_global_load_lds( \
            AS1(Kp + (ktrow + row_) * 768 + (H_) * 64 + c_ * 8), \
            AS3(Kb + (BUF) * 8192 + j_ * 4096 + wbase16), 16, 0, 0); \
    } } while (0)

#define MBODY(H_, CUR) do { \
    const f16* Qb_ = (const f16*)(Qb + (CUR) * 8192); \
    const f16* Kb_ = (const f16*)(Kb + (CUR) * 8192); \
    f16x8 qf[4]; \
    _Pragma("unroll") \
    for (int d_ = 0; d_ < 4; ++d_) qf[d_] = FRAG32(Qb_, qh * 32, d_ * 2 + hi); \
    f32x16 sa; \
    _Pragma("unroll") \
    for (int r_ = 0; r_ < 16; ++r_) sa[r_] = 0.f; \
    sa = MFMA32(FRAG32(Kb_, kh * 32, 0 + hi), qf[0], sa); \
    sa = MFMA32(FRAG32(Kb_, kh * 32, 2 + hi), qf[1], sa); \
    sa = MFMA32(FRAG32(Kb_, kh * 32, 4 + hi), qf[2], sa); \
    sa = MFMA32(FRAG32(Kb_, kh * 32, 6 + hi), qf[3], sa); \
    const float ivv = l_inv[((size_t)(b * 12 + (H_))) * 2048 + qt * 64 + qh * 32 + q32]; \
    _Pragma("unroll") \
    for (int r_ = 0; r_ < 16; ++r_) macc[r_] += EXP2(sa[r_]) * ivv; \
} while (0)

        MSTAGE(0, 0);
        __syncthreads();
        for (int h = 0; h < 12; ++h) {
            const int cur = h & 1;
            if (h < 11) MSTAGE(h + 1, cur ^ 1);
            MBODY(h, cur);
            __syncthreads();
        }
#undef MSTAGE
#undef MBODY

        float* ob = om + ((size_t)(b * 2048 + qt * 64 + qh * 32 + q32)) * 2048
                  + kt * 64 + kh * 32;
#pragma unroll
        for (int g = 0; g < 4; ++g) {
            float4 v4 = { macc[g * 4 + 0] * (1.0f / 12.0f),
                          macc[g * 4 + 1] * (1.0f / 12.0f),
                          macc[g * 4 + 2] * (1.0f / 12.0f),
                          macc[g * 4 + 3] * (1.0f / 12.0f) };
            *(float4*)(ob + g * 8 + hi * 4) = v4;
        }
    }
}

// ---------------- launch ----------------
extern "C" void kernel_launch(void* const* d_in, const int* in_sizes, int n_in,
                              void* d_out, int out_size, void* d_ws, size_t ws_size,
                              hipStream_t stream) {
    const float* q  = (const float*)d_in[0];
    const float* k  = (const float*)d_in[1];
    const float* v  = (const float*)d_in[2];
    const float* Wq = (const float*)d_in[3];
    const float* bq = (const float*)d_in[4];
    const float* Wk = (const float*)d_in[5];
    const float* bk = (const float*)d_in[6];
    const float* Wv = (const float*)d_in[7];
    const float* bv = (const float*)d_in[8];
    const float* Wo = (const float*)d_in[9];
    const float* bo = (const float*)d_in[10];
    float* out = (float*)d_out;

    char* ws = (char*)d_ws;
    const size_t SZ_IN = (size_t)Mc * Dc * 2;
    const size_t SZ_W  = (size_t)Dc * Dc * 2;
    f16* qh  = (f16*)(ws);
    f16* kh  = (f16*)(ws + SZ_IN);
    f16* vh  = (f16*)(ws + 2 * SZ_IN);
    f16* wqh = (f16*)(ws + 3 * SZ_IN);
    f16* wkh = (f16*)(ws + 3 * SZ_IN + SZ_W);
    f16* wvh = (f16*)(ws + 3 * SZ_IN + 2 * SZ_W);
    f16* woh = (f16*)(ws + 3 * SZ_IN + 3 * SZ_W);
    f16* Qp  = (f16*)(ws + 3 * SZ_IN + 4 * SZ_W);
    f16* Kp  = (f16*)(ws + 4 * SZ_IN + 4 * SZ_W);
    f16* Vt  = (f16*)(ws + 5 * SZ_IN + 4 * SZ_W);
    f16* ctx = qh;                 // dead-buffer reuse
    float* l_inv = (float*)kh;     // dead-buffer reuse

    conv_all<<<dim3(11520), dim3(256), 0, stream>>>(q, k, v, Wq, Wk, Wv, Wo,
                                                    qh, kh, vh, wqh, wkh, wvh, woh);
    qkv_proj<<<dim3(12, 32, 3), dim3(256), 0, stream>>>(qh, kh, vh, wqh, wkh, wvh,
                                                        bq, bk, bv, Qp, Kp, Vt);
    attn_out<<<dim3(32, 12, 2), dim3(256), 0, stream>>>(Qp, Kp, Vt, l_inv, ctx);
    tail_fused<<<dim3(2432), dim3(256), 0, stream>>>(ctx, woh, bo, out,
                                                     Qp, Kp, l_inv,
                                                     out + (size_t)Mc * Dc);
}

// Round 12
// 129.517 us; speedup vs baseline: 1.0564x; 1.0088x over previous
//
#include <hip/hip_runtime.h>
#include <hip/hip_fp16.h>
#include <stdint.h>

typedef _Float16 f16;
typedef _Float16 f16x8 __attribute__((ext_vector_type(8)));
typedef _Float16 f16x4v __attribute__((ext_vector_type(4)));
typedef __fp16 h16x2 __attribute__((ext_vector_type(2)));   // cvt_pkrtz return type
typedef float f32x4 __attribute__((ext_vector_type(4)));
typedef float f32x16 __attribute__((ext_vector_type(16)));

#define MFMA32(a,b,c) __builtin_amdgcn_mfma_f32_32x32x16_f16(a,b,c,0,0,0)
#define CVTPK(a,b) __builtin_amdgcn_cvt_pkrtz(a,b)

#if __has_builtin(__builtin_amdgcn_exp2f)
#define EXP2(x) __builtin_amdgcn_exp2f(x)
#else
#define EXP2(x) exp2f(x)
#endif

static __device__ __forceinline__ float dot2acc(h16x2 a, float c) {
#if __has_builtin(__builtin_amdgcn_fdot2)
    const h16x2 one = { (__fp16)1.f, (__fp16)1.f };
    return __builtin_amdgcn_fdot2(a, one, c, false);
#else
    return c + (float)a[0] + (float)a[1];
#endif
}

typedef __attribute__((address_space(1))) void gvoid_t;
typedef __attribute__((address_space(3))) void svoid_t;
#define AS1(p) ((gvoid_t*)(uintptr_t)(p))
#define AS3(p) ((svoid_t*)(uint32_t)(uintptr_t)(p))

static constexpr int Bc = 2, Tc = 2048, Dc = 768, Hc = 12;
static constexpr int Mc = Bc * Tc;                      // 4096
static constexpr float SC2 = 0.18033688011112042f;      // (1/8) * log2(e), folded into Wq/bq

union PA { f16x8 v; h16x2 h[4]; };

// Swizzle key: folds row bits 3-4 in so rows differing by 8/16/24 get distinct chunks
// (fixes the 2-way conflict of lanes l and l+16 under the row&7 key).
#define FKEY(R) ((((R) & 7)) ^ (((R) >> 3) & 3))

// FRAG32: tiles [rows][8 chunks of 16B] (128B rows), storage chunk = logical ^ FKEY(row).
// ROWOFF multiple of 32 -> FKEY(ROWOFF + q32) == FKEY(q32).
#define FRAG32(BASE, ROWOFF, CHUNK) \
    (*(const f16x8*)((const char*)(BASE) + \
        ((ROWOFF) + q32) * 128 + (((CHUNK) ^ FKEY(q32)) * 16)))

// FRAGP: row-pair layout for BK=32 tiles. Line L=row/2 (128B), chunk8 = (row&1)*4 + c16,
// stored at chunk8 ^ FKEY(L). ROWOFF must be a multiple of 32.
#define FRAGP(BASE, ROWOFF, C) \
    (*(const f16x8*)((const char*)(BASE) + \
        (((ROWOFF) / 2 + (q32 >> 1)) * 128) + \
        (((((q32 & 1) << 2) | (C)) ^ FKEY((ROWOFF) / 2 + (q32 >> 1))) * 16)))

// ---------------- f32 -> f16 conversion (all inputs + weights; Wq pre-scaled) ----------------
__global__ __launch_bounds__(256) void conv_all(
    const float* __restrict__ q, const float* __restrict__ k, const float* __restrict__ v,
    const float* __restrict__ wq, const float* __restrict__ wk, const float* __restrict__ wv,
    const float* __restrict__ wo,
    f16* __restrict__ qh, f16* __restrict__ kh, f16* __restrict__ vh,
    f16* __restrict__ wqh, f16* __restrict__ wkh, f16* __restrict__ wvh, f16* __restrict__ woh)
{
    const int NI = (Mc * Dc) / 4;
    const int NW = (Dc * Dc) / 4;
    int i = blockIdx.x * 256 + threadIdx.x;
    if (i >= 3 * NI + 4 * NW) return;
    const float4* src; f16* dst; int j; float scl = 1.f;
    if (i < 3 * NI) {
        int a = i / NI; j = i - a * NI;
        src = (const float4*)(a == 0 ? q : (a == 1 ? k : v));
        dst = (a == 0 ? qh : (a == 1 ? kh : vh));
    } else {
        int t = i - 3 * NI;
        int a = t / NW; j = t - a * NW;
        src = (const float4*)(a == 0 ? wq : (a == 1 ? wk : (a == 2 ? wv : wo)));
        dst = (a == 0 ? wqh : (a == 1 ? wkh : (a == 2 ? wvh : woh)));
        if (a == 0) scl = SC2;
    }
    float4 f = src[j];
    f16x4v o = { (f16)(f.x * scl), (f16)(f.y * scl), (f16)(f.z * scl), (f16)(f.w * scl) };
    *(f16x4v*)(dst + 4 * j) = o;
}

// ------- 128x64 GEMM mainloop, BK=32, MFMA32, row-pair swizzled tiles, dbuf (24 KiB) -------
// As: 2 x 8 KiB (A tile 128x32). Bs: 2 x 4 KiB (W tile 64x32). acc[mi]: rows wr*64+mi*32.
__device__ __forceinline__ void gemm_bk32(
    const f16* __restrict__ A, const f16* __restrict__ W,
    int brow, int bcol, char* As, char* Bs, f32x16 acc[2])
{
    const int tid = threadIdx.x;
    const int w = tid >> 6, lane = tid & 63;
    const int q32 = lane & 31, hi = lane >> 5;
    const int wr = w >> 1, wc = w & 1;
    const int wbase16 = (tid & ~63) * 16;

#define GSA(KT_, BUF_) do { \
    const int k0_ = (KT_) * 32; \
    _Pragma("unroll") \
    for (int j_ = 0; j_ < 2; ++j_) { \
        const int p_ = j_ * 256 + tid; \
        const int L_ = p_ >> 3, c8_ = (p_ & 7) ^ FKEY(L_); \
        const int row_ = 2 * L_ + (c8_ >> 2), kc_ = (c8_ & 3) * 8; \
        __builtin_amdgcn_global_load_lds(AS1(A + (size_t)(brow + row_) * 768 + k0_ + kc_), \
            AS3(As + (BUF_) * 8192 + j_ * 4096 + wbase16), 16, 0, 0); \
    } } while (0)
#define GSB(KT_, BUF_) do { \
    const int k0_ = (KT_) * 32; \
    const int L_ = tid >> 3, c8_ = (tid & 7) ^ FKEY(L_); \
    const int row_ = 2 * L_ + (c8_ >> 2), kc_ = (c8_ & 3) * 8; \
    __builtin_amdgcn_global_load_lds(AS1(W + (size_t)(bcol + row_) * 768 + k0_ + kc_), \
        AS3(Bs + (BUF_) * 4096 + wbase16), 16, 0, 0); \
    } while (0)

    GSA(0, 0); GSB(0, 0);
    __syncthreads();
    for (int kt = 0; kt < 24; ++kt) {
        const int cur = kt & 1;
        if (kt < 23) { GSA(kt + 1, cur ^ 1); GSB(kt + 1, cur ^ 1); }
        const char* As_ = As + cur * 8192;
        const char* Bs_ = Bs + cur * 4096;
#pragma unroll
        for (int ks = 0; ks < 2; ++ks) {
            const f16x8 af0 = FRAGP(As_, wr * 64,      ks * 2 + hi);
            const f16x8 af1 = FRAGP(As_, wr * 64 + 32, ks * 2 + hi);
            const f16x8 bf  = FRAGP(Bs_, wc * 32,      ks * 2 + hi);
            acc[0] = MFMA32(af0, bf, acc[0]);
            acc[1] = MFMA32(af1, bf, acc[1]);
        }
        __syncthreads();
    }
#undef GSA
#undef GSB
}

// ---------------- QKV projections (z: 0=Q-scaled, 1=K, 2=V via LDS transpose) ----------------
__global__ __launch_bounds__(256) void qkv_proj(
    const f16* __restrict__ qh, const f16* __restrict__ kh, const f16* __restrict__ vh,
    const f16* __restrict__ wqh, const f16* __restrict__ wkh, const f16* __restrict__ wvh,
    const float* __restrict__ bq, const float* __restrict__ bk, const float* __restrict__ bv,
    f16* __restrict__ Qp, f16* __restrict__ Kp, f16* __restrict__ Vt)
{
    __shared__ char lds[24576];
    char* As = lds; char* Bs = lds + 16384;

    const int z = blockIdx.z;
    const f16* A = (z == 0) ? qh : (z == 1) ? kh : vh;
    const f16* W = (z == 0) ? wqh : (z == 1) ? wkh : wvh;
    const float* bias = (z == 0) ? bq : (z == 1) ? bk : bv;
    const int brow = blockIdx.y * 128, bcol = blockIdx.x * 64;

    f32x16 acc[2];
#pragma unroll
    for (int mi = 0; mi < 2; ++mi)
#pragma unroll
        for (int r = 0; r < 16; ++r) acc[mi][r] = 0.f;

    gemm_bk32(A, W, brow, bcol, As, Bs, acc);

    const int tid = threadIdx.x, w = tid >> 6, lane = tid & 63;
    const int q32 = lane & 31, hi = lane >> 5;
    const int wr = w >> 1, wc = w & 1;
    const int c = bcol + wc * 32 + q32;
    const float bval = (z == 0) ? bias[c] * SC2 : bias[c];

    if (z < 2) {
        f16* dst = (z == 0) ? Qp : Kp;
#pragma unroll
        for (int mi = 0; mi < 2; ++mi)
#pragma unroll
            for (int r = 0; r < 16; ++r) {
                const int row = brow + wr * 64 + mi * 32 + (r & 3) + 8 * (r >> 2) + 4 * hi;
                dst[(size_t)row * 768 + c] = (f16)(acc[mi][r] + bval);
            }
    } else {
        // V: transpose in LDS (reuse As region, 16 KiB), then coalesced stores.
        __syncthreads();
        const int dl = wc * 32 + q32;
#pragma unroll
        for (int mi = 0; mi < 2; ++mi)
#pragma unroll
            for (int j = 0; j < 8; ++j) {
                const int r0 = 2 * j;
                const int crow = (r0 & 3) + 8 * (r0 >> 2) + 4 * hi;     // even, < 32
                const int sw = ((crow >> 2) ^ (crow >> 3)) & 1;         // sigma involution
                const int tp = crow ^ (sw * 12);
                const int tloc = wr * 64 + mi * 32 + tp;
                const h16x2 pv = CVTPK(acc[mi][r0] + bval, acc[mi][r0 + 1] + bval);
                *(h16x2*)(As + dl * 256 + ((tloc * 2) ^ ((dl & 7) << 4))) = pv;
            }
        __syncthreads();
        const int bb = brow >> 11, t0 = brow & 2047, hh = bcol >> 6;
        f16* Vh = Vt + ((size_t)(bb * 12 + hh) * 64) * 2048;
#pragma unroll
        for (int j = 0; j < 4; ++j) {
            const int dr = j * 16 + (tid >> 4), off = tid & 15;
            const f16x8 vv = *(const f16x8*)(As + dr * 256 + ((off * 16) ^ ((dr & 7) << 4)));
            *(f16x8*)(Vh + (size_t)dr * 2048 + t0 + off * 8) = vv;
        }
    }
}

// ---------------- fused attention, 32x32x16 MFMA, 4 waves = (q-half, k-half) ----------------
// LDS: single 33 KiB arena. Main loop uses Kbuf/Vbuf (32 KiB); epilogue reuses the same
// bytes as Ored (16 KiB) + lred (after last main-loop barrier both phases are disjoint).
__global__ __launch_bounds__(256, 4) void attn_out(
    const f16* __restrict__ Qp, const f16* __restrict__ Kp, const f16* __restrict__ Vt,
    float* __restrict__ l_inv, f16* __restrict__ ctx)
{
    __shared__ char arena[33280];   // 32 KiB Kbuf/Vbuf  |  epilogue: Ored 16 KiB + lred 512 B

    f16* Kbuf0 = (f16*)(arena);            // [4096]
    f16* Kbuf1 = (f16*)(arena + 8192);
    f16* Vbuf0 = (f16*)(arena + 16384);
    f16* Vbuf1 = (f16*)(arena + 24576);
    float (*Ored)[32][64] = (float (*)[32][64])(arena);          // [2][32][64]
    float (*lred)[2][32]  = (float (*)[2][32])(arena + 16384);   // [2][2][32]

    const int qt = blockIdx.x, h = blockIdx.y, b = blockIdx.z;
    const int tid = threadIdx.x, w = tid >> 6, lane = tid & 63;
    const int q32 = lane & 31, hi = lane >> 5;
    const int qh = w & 1, kh = w >> 1;
    const int wbase16 = (tid & ~63) * 16;

    const size_t qrow0 = (size_t)b * 2048 + qt * 64 + qh * 32;
    const int hcol = h * 64;

    const f16* qb = Qp + (qrow0 + q32) * 768 + hcol + hi * 8;
    f16x8 bqf[4];
#pragma unroll
    for (int d = 0; d < 4; ++d) bqf[d] = *(const f16x8*)(qb + d * 16);

    const size_t kbase = (size_t)b * 2048;
    const f16* Vg = Vt + ((size_t)(b * 12 + h)) * 64 * 2048;

    f32x16 oacc[2];
#pragma unroll
    for (int dt = 0; dt < 2; ++dt)
#pragma unroll
        for (int r = 0; r < 16; ++r) oacc[dt][r] = 0.f;
    float lsum = 0.f;

#define STAGE_KV(KT_, KB_, VB_) do { \
    _Pragma("unroll") \
    for (int j_ = 0; j_ < 2; ++j_) { \
        const int p_ = j_ * 256 + tid; \
        const int row_ = p_ >> 3, c_ = (p_ & 7) ^ FKEY(row_); \
        __builtin_amdgcn_global_load_lds( \
            AS1(Kp + (kbase + (size_t)(KT_) * 64 + row_) * 768 + hcol + c_ * 8), \
            AS3((char*)(KB_) + j_ * 4096 + wbase16), 16, 0, 0); \
        __builtin_amdgcn_global_load_lds( \
            AS1(Vg + (size_t)row_ * 2048 + (KT_) * 64 + c_ * 8), \
            AS3((char*)(VB_) + j_ * 4096 + wbase16), 16, 0, 0); \
    } } while (0)

#define AOBODY(KB_, VB_) do { \
    const f16* Kb_ = (KB_); const f16* Vb_ = (VB_); \
    f32x16 sa; \
    _Pragma("unroll") \
    for (int r_ = 0; r_ < 16; ++r_) sa[r_] = 0.f; \
    sa = MFMA32(FRAG32(Kb_, kh * 32, 0 + hi), bqf[0], sa); \
    sa = MFMA32(FRAG32(Kb_, kh * 32, 2 + hi), bqf[1], sa); \
    sa = MFMA32(FRAG32(Kb_, kh * 32, 4 + hi), bqf[2], sa); \
    sa = MFMA32(FRAG32(Kb_, kh * 32, 6 + hi), bqf[3], sa); \
    float p[16]; \
    _Pragma("unroll") \
    for (int r_ = 0; r_ < 16; ++r_) p[r_] = EXP2(sa[r_]); \
    PA pa0, pa1; \
    pa0.h[0] = CVTPK(p[0], p[1]);   pa0.h[1] = CVTPK(p[2], p[3]); \
    pa0.h[2] = CVTPK(p[4], p[5]);   pa0.h[3] = CVTPK(p[6], p[7]); \
    pa1.h[0] = CVTPK(p[8], p[9]);   pa1.h[1] = CVTPK(p[10], p[11]); \
    pa1.h[2] = CVTPK(p[12], p[13]); pa1.h[3] = CVTPK(p[14], p[15]); \
    float t0_ = 0.f, t1_ = 0.f; \
    t0_ = dot2acc(pa0.h[0], t0_); t0_ = dot2acc(pa0.h[1], t0_); \
    t0_ = dot2acc(pa0.h[2], t0_); t0_ = dot2acc(pa0.h[3], t0_); \
    t1_ = dot2acc(pa1.h[0], t1_); t1_ = dot2acc(pa1.h[1], t1_); \
    t1_ = dot2acc(pa1.h[2], t1_); t1_ = dot2acc(pa1.h[3], t1_); \
    lsum += t0_ + t1_; \
    oacc[0] = MFMA32(FRAG32(Vb_, 0,  kh * 4 + 0 + hi), pa0.v, oacc[0]); \
    oacc[0] = MFMA32(FRAG32(Vb_, 0,  kh * 4 + 2 + hi), pa1.v, oacc[0]); \
    oacc[1] = MFMA32(FRAG32(Vb_, 32, kh * 4 + 0 + hi), pa0.v, oacc[1]); \
    oacc[1] = MFMA32(FRAG32(Vb_, 32, kh * 4 + 2 + hi), pa1.v, oacc[1]); \
} while (0)

    STAGE_KV(0, Kbuf0, Vbuf0);
    __syncthreads();
    for (int kt = 0; kt < 32; kt += 2) {
        STAGE_KV(kt + 1, Kbuf1, Vbuf1);
        AOBODY(Kbuf0, Vbuf0);
        __syncthreads();
        if (kt < 30) STAGE_KV(kt + 2, Kbuf0, Vbuf0);
        AOBODY(Kbuf1, Vbuf1);
        __syncthreads();
    }
#undef STAGE_KV
#undef AOBODY

    // ---- epilogue: arena reused as Ored/lred (all Kbuf/Vbuf reads completed) ----
    lsum += __shfl_xor(lsum, 32);
    if (hi == 0) lred[kh][qh][q32] = lsum;
    if (kh == 1) {
#pragma unroll
        for (int dt = 0; dt < 2; ++dt)
#pragma unroll
            for (int g = 0; g < 4; ++g) {
                float4 v4 = { oacc[dt][g * 4 + 0], oacc[dt][g * 4 + 1],
                              oacc[dt][g * 4 + 2], oacc[dt][g * 4 + 3] };
                *(float4*)&Ored[qh][q32][dt * 32 + g * 8 + hi * 4] = v4;
            }
    }
    __syncthreads();
    if (kh == 0) {
        const float iv = 1.f / (lred[0][qh][q32] + lred[1][qh][q32]);
        if (hi == 0)
            l_inv[((size_t)(b * 12 + h)) * 2048 + qt * 64 + qh * 32 + q32] = iv;
        f16* cb = ctx + (qrow0 + q32) * 768 + hcol;
#pragma unroll
        for (int dt = 0; dt < 2; ++dt)
#pragma unroll
            for (int g = 0; g < 4; ++g) {
                const int d0 = dt * 32 + g * 8 + hi * 4;
                const float4 o4 = *(const float4*)&Ored[qh][q32][d0];
                f16x4v s;
#pragma unroll
                for (int e = 0; e < 4; ++e)
                    s[e] = (f16)((oacc[dt][g * 4 + e] + (&o4.x)[e]) * iv);
                *(f16x4v*)(cb + d0) = s;
            }
    }
}

// ------- fused tail: blocks [0,384) = out_proj (BK32 gemm), [384,2432) = attn_mean 64x64 -------
__global__ __launch_bounds__(256) void tail_fused(
    const f16* __restrict__ ctx, const f16* __restrict__ woh,
    const float* __restrict__ bo, float* __restrict__ out,
    const f16* __restrict__ Qp, const f16* __restrict__ Kp,
    const float* __restrict__ l_inv, float* __restrict__ om)
{
    __shared__ char sh[32768];   // 32 KiB

    const int tid = threadIdx.x, w = tid >> 6, lane = tid & 63;
    const int q32 = lane & 31, hi = lane >> 5;
    const int wbase16 = (tid & ~63) * 16;

    if (blockIdx.x < 384) {
        // ================= out_proj =================
        const int brow = (blockIdx.x / 12) * 128, bcol = (blockIdx.x % 12) * 64;
        f32x16 acc[2];
#pragma unroll
        for (int mi = 0; mi < 2; ++mi)
#pragma unroll
            for (int r = 0; r < 16; ++r) acc[mi][r] = 0.f;

        gemm_bk32(ctx, woh, brow, bcol, sh, sh + 16384, acc);

        const int wr = w >> 1, wc = w & 1;
        const int c = bcol + wc * 32 + q32;
        const float bval = bo[c];
#pragma unroll
        for (int mi = 0; mi < 2; ++mi)
#pragma unroll
            for (int r = 0; r < 16; ++r) {
                const int row = brow + wr * 64 + mi * 32 + (r & 3) + 8 * (r >> 2) + 4 * hi;
                out[(size_t)row * 768 + c] = acc[mi][r] + bval;
            }
    } else {
        // ================= attn_mean: 64 q x 64 k per block, 4 waves = (qh, kh) =================
        const int mb = blockIdx.x - 384;              // [0, 2048)
        const int kt = mb & 31, r2 = mb >> 5;
        const int qt = r2 & 31, b = r2 >> 5;
        const int qh = w & 1, kh = w >> 1;

        char* Qb = sh;            // 2 x 8 KiB
        char* Kb = sh + 16384;    // 2 x 8 KiB

        const size_t qtrow = (size_t)b * 2048 + qt * 64;
        const size_t ktrow = (size_t)b * 2048 + kt * 64;

        f32x16 macc;
#pragma unroll
        for (int r = 0; r < 16; ++r) macc[r] = 0.f;

#define MSTAGE(H_, BUF) do { \
    _Pragma("unroll") \
    for (int j_ = 0; j_ < 2; ++j_) { \
        const int p_ = j_ * 256 + tid; \
        const int row_ = p_ >> 3, c_ = (p_ & 7) ^ FKEY(row_); \
        __builtin_amdgcn_global_load_lds( \
            AS1(Qp + (qtrow + row_) * 768 + (H_) * 64 + c_ * 8), \
            AS3(Qb + (BUF) * 8192 + j_ * 4096 + wbase16), 16, 0, 0); \
        __builtin_amdgcn_global_load_lds( \
            AS1(Kp + (ktrow + row_) * 768 + (H_) * 64 + c_ * 8), \
            AS3(Kb + (BUF) * 8192 + j_ * 4096 + wbase16), 16, 0, 0); \
    } } while (0)

#define MBODY(H_, CUR) do { \
    const f16* Qb_ = (const f16*)(Qb + (CUR) * 8192); \
    const f16* Kb_ = (const f16*)(Kb + (CUR) * 8192); \
    f16x8 qf[4]; \
    _Pragma("unroll") \
    for (int d_ = 0; d_ < 4; ++d_) qf[d_] = FRAG32(Qb_, qh * 32, d_ * 2 + hi); \
    f32x16 sa; \
    _Pragma("unroll") \
    for (int r_ = 0; r_ < 16; ++r_) sa[r_] = 0.f; \
    sa = MFMA32(FRAG32(Kb_, kh * 32, 0 + hi), qf[0], sa); \
    sa = MFMA32(FRAG32(Kb_, kh * 32, 2 + hi), qf[1], sa); \
    sa = MFMA32(FRAG32(Kb_, kh * 32, 4 + hi), qf[2], sa); \
    sa = MFMA32(FRAG32(Kb_, kh * 32, 6 + hi), qf[3], sa); \
    const float ivv = l_inv[((size_t)(b * 12 + (H_))) * 2048 + qt * 64 + qh * 32 + q32]; \
    _Pragma("unroll") \
    for (int r_ = 0; r_ < 16; ++r_) macc[r_] += EXP2(sa[r_]) * ivv; \
} while (0)

        MSTAGE(0, 0);
        __syncthreads();
        for (int h = 0; h < 12; ++h) {
            const int cur = h & 1;
            if (h < 11) MSTAGE(h + 1, cur ^ 1);
            MBODY(h, cur);
            __syncthreads();
        }
#undef MSTAGE
#undef MBODY

        float* ob = om + ((size_t)(b * 2048 + qt * 64 + qh * 32 + q32)) * 2048
                  + kt * 64 + kh * 32;
#pragma unroll
        for (int g = 0; g < 4; ++g) {
            float4 v4 = { macc[g * 4 + 0] * (1.0f / 12.0f),
                          macc[g * 4 + 1] * (1.0f / 12.0f),
                          macc[g * 4 + 2] * (1.0f / 12.0f),
                          macc[g * 4 + 3] * (1.0f / 12.0f) };
            *(float4*)(ob + g * 8 + hi * 4) = v4;
        }
    }
}

// ---------------- launch ----------------
extern "C" void kernel_launch(void* const* d_in, const int* in_sizes, int n_in,
                              void* d_out, int out_size, void* d_ws, size_t ws_size,
                              hipStream_t stream) {
    const float* q  = (const float*)d_in[0];
    const float* k  = (const float*)d_in[1];
    const float* v  = (const float*)d_in[2];
    const float* Wq = (const float*)d_in[3];
    const float* bq = (const float*)d_in[4];
    const float* Wk = (const float*)d_in[5];
    const float* bk = (const float*)d_in[6];
    const float* Wv = (const float*)d_in[7];
    const float* bv = (const float*)d_in[8];
    const float* Wo = (const float*)d_in[9];
    const float* bo = (const float*)d_in[10];
    float* out = (float*)d_out;

    char* ws = (char*)d_ws;
    const size_t SZ_IN = (size_t)Mc * Dc * 2;
    const size_t SZ_W  = (size_t)Dc * Dc * 2;
    f16* qh  = (f16*)(ws);
    f16* kh  = (f16*)(ws + SZ_IN);
    f16* vh  = (f16*)(ws + 2 * SZ_IN);
    f16* wqh = (f16*)(ws + 3 * SZ_IN);
    f16* wkh = (f16*)(ws + 3 * SZ_IN + SZ_W);
    f16* wvh = (f16*)(ws + 3 * SZ_IN + 2 * SZ_W);
    f16* woh = (f16*)(ws + 3 * SZ_IN + 3 * SZ_W);
    f16* Qp  = (f16*)(ws + 3 * SZ_IN + 4 * SZ_W);
    f16* Kp  = (f16*)(ws + 4 * SZ_IN + 4 * SZ_W);
    f16* Vt  = (f16*)(ws + 5 * SZ_IN + 4 * SZ_W);
    f16* ctx = qh;                 // dead-buffer reuse
    float* l_inv = (float*)kh;     // dead-buffer reuse

    conv_all<<<dim3(11520), dim3(256), 0, stream>>>(q, k, v, Wq, Wk, Wv, Wo,
                                                    qh, kh, vh, wqh, wkh, wvh, woh);
    qkv_proj<<<dim3(12, 32, 3), dim3(256), 0, stream>>>(qh, kh, vh, wqh, wkh, wvh,
                                                        bq, bk, bv, Qp, Kp, Vt);
    attn_out<<<dim3(32, 12, 2), dim3(256), 0, stream>>>(Qp, Kp, Vt, l_inv, ctx);
    tail_fused<<<dim3(2432), dim3(256), 0, stream>>>(ctx, woh, bo, out,
                                                     Qp, Kp, l_inv,
                                                     out + (size_t)Mc * Dc);
}